// Round 2
// baseline (442.717 us; speedup 1.0000x reference)
//
#include <hip/hip_runtime.h>

#define NUM_A    400000
#define NUM_G    64
#define TOPK     10
#define CHUNKS   32
#define CHUNK_SZ (NUM_A / CHUNKS)   // 12500
#define GGROUP   4                  // GTs per K1 block
#define NGROUPS  (NUM_G / GGROUP)   // 16

// top_k ordering: larger value first; ties -> lower anchor index first.
__device__ __forceinline__ bool better(float m1, int a1, float m2, int a2) {
    return (m1 > m2) || ((m1 == m2) && (a1 < a2));
}

__device__ __forceinline__ float metric_eval(
    float x, float y,
    float px1, float py1, float px2, float py2, float parea, float score,
    float gx1, float gy1, float gx2, float gy2, float garea)
{
    bool in_gt = (x >= gx1) && (x <= gx2) && (y >= gy1) && (y <= gy2);
    float ltx = fmaxf(px1, gx1);
    float lty = fmaxf(py1, gy1);
    float rbx = fminf(px2, gx2);
    float rby = fminf(py2, gy2);
    float w = fmaxf(rbx - ltx, 0.0f);
    float h = fmaxf(rby - lty, 0.0f);
    float inter = w * h;
    float iou = inter / (parea + garea - inter);   // denom >= 64 always
    float iou2 = iou * iou;
    float iou6 = iou2 * iou2 * iou2;
    float cls = in_gt ? score : 0.0f;
    return cls * iou6;
}

// K1: block = (chunk c, gt-group gg). Per-thread register top-10 (value,idx)
// per GT in group, then LDS tree merge. Output: sorted top-10 pairs per (g,c).
__global__ __launch_bounds__(256) void topk_partial_kernel(
    const float* __restrict__ pd_scores,
    const float* __restrict__ pd_bboxes,
    const float* __restrict__ anc_points,
    const float* __restrict__ gt_bboxes,
    float* __restrict__ pval,
    int*   __restrict__ pidx)
{
    const int c   = blockIdx.x;
    const int gg  = blockIdx.y;
    const int tid = threadIdx.x;
    const int g0  = gg * GGROUP;

    float gx1[GGROUP], gy1[GGROUP], gx2[GGROUP], gy2[GGROUP], ga[GGROUP];
#pragma unroll
    for (int j = 0; j < GGROUP; ++j) {
        float4 gb = ((const float4*)gt_bboxes)[g0 + j];
        gx1[j] = gb.x; gy1[j] = gb.y; gx2[j] = gb.z; gy2[j] = gb.w;
        ga[j] = (gb.z - gb.x) * (gb.w - gb.y);
    }

    float tv[GGROUP][TOPK];
    int   ti[GGROUP][TOPK];
#pragma unroll
    for (int j = 0; j < GGROUP; ++j)
#pragma unroll
        for (int k = 0; k < TOPK; ++k) { tv[j][k] = -1.0f; ti[j][k] = 0x7fffffff; }

    const int a0 = c * CHUNK_SZ, a1 = a0 + CHUNK_SZ;
    for (int a = a0 + tid; a < a1; a += 256) {
        float2 ap = ((const float2*)anc_points)[a];
        float4 pb = ((const float4*)pd_bboxes)[a];
        float parea = (pb.z - pb.x) * (pb.w - pb.y);
        float score = pd_scores[a];   // NUM_CLASSES == 1
#pragma unroll
        for (int j = 0; j < GGROUP; ++j) {
            float m = metric_eval(ap.x, ap.y, pb.x, pb.y, pb.z, pb.w, parea,
                                  score, gx1[j], gy1[j], gx2[j], gy2[j], ga[j]);
            if (better(m, a, tv[j][TOPK - 1], ti[j][TOPK - 1])) {
                // unrolled sorted insert; k descending reads t[k-1] pre-update
#pragma unroll
                for (int k = TOPK - 1; k >= 1; --k) {
                    bool gp = better(m, a, tv[j][k - 1], ti[j][k - 1]);
                    bool gc = better(m, a, tv[j][k],     ti[j][k]);
                    tv[j][k] = gp ? tv[j][k - 1] : (gc ? m : tv[j][k]);
                    ti[j][k] = gp ? ti[j][k - 1] : (gc ? a : ti[j][k]);
                }
                if (better(m, a, tv[j][0], ti[j][0])) { tv[j][0] = m; ti[j][0] = a; }
            }
        }
    }

    __shared__ float sv[256 * TOPK];
    __shared__ int   si[256 * TOPK];
    for (int j = 0; j < GGROUP; ++j) {
        __syncthreads();   // protect LDS writes vs previous iteration's reads
#pragma unroll
        for (int k = 0; k < TOPK; ++k) {
            sv[tid * TOPK + k] = tv[j][k];
            si[tid * TOPK + k] = ti[j][k];
        }
        for (int off = 128; off >= 1; off >>= 1) {
            __syncthreads();
            if (tid < off) {
                const int rA = tid * TOPK, rB = (tid + off) * TOPK;
                float mv[TOPK]; int mi[TOPK];
                int ia = 0, ib = 0;
#pragma unroll
                for (int k = 0; k < TOPK; ++k) {     // ia,ib <= k <= 9: in range
                    float va = sv[rA + ia], vb = sv[rB + ib];
                    int   na = si[rA + ia], nb = si[rB + ib];
                    bool tA = better(va, na, vb, nb);
                    mv[k] = tA ? va : vb;
                    mi[k] = tA ? na : nb;
                    ia += tA ? 1 : 0;
                    ib += tA ? 0 : 1;
                }
#pragma unroll
                for (int k = 0; k < TOPK; ++k) { sv[rA + k] = mv[k]; si[rA + k] = mi[k]; }
            }
        }
        __syncthreads();
        if (tid < TOPK) {
            const int g = g0 + j;
            pval[(g * CHUNKS + c) * TOPK + tid] = sv[tid];
            pidx[(g * CHUNKS + c) * TOPK + tid] = si[tid];
        }
    }
}

// K2: thread g merges its 32 sorted lists (320 pairs) -> exact top-10 anchor
// ids for column g; marks flags[a]=1 for those with value > 0.
__global__ __launch_bounds__(64) void merge_scatter_kernel(
    const float* __restrict__ pval,
    const int*   __restrict__ pidx,
    unsigned char* __restrict__ flags)
{
    const int g = threadIdx.x;
    float tv[TOPK]; int ti[TOPK];
#pragma unroll
    for (int k = 0; k < TOPK; ++k) { tv[k] = -1.0f; ti[k] = 0x7fffffff; }
    const float* pv = pval + g * CHUNKS * TOPK;
    const int*   pi = pidx + g * CHUNKS * TOPK;
    for (int i = 0; i < CHUNKS * TOPK; ++i) {
        float m = pv[i];
        int   a = pi[i];
        if (better(m, a, tv[TOPK - 1], ti[TOPK - 1])) {
#pragma unroll
            for (int k = TOPK - 1; k >= 1; --k) {
                bool gp = better(m, a, tv[k - 1], ti[k - 1]);
                bool gc = better(m, a, tv[k],     ti[k]);
                tv[k] = gp ? tv[k - 1] : (gc ? m : tv[k]);
                ti[k] = gp ? ti[k - 1] : (gc ? a : ti[k]);
            }
            if (better(m, a, tv[0], ti[0])) { tv[0] = m; ti[0] = a; }
        }
    }
#pragma unroll
    for (int k = 0; k < TOPK; ++k)
        if (tv[k] > 0.0f) flags[ti[k]] = 1;   // same-value byte races benign
}

// K3: fg from flags (exact); idx = fg ? argmax_g metric : 0 (first-max).
__global__ __launch_bounds__(256) void assign_kernel(
    const float* __restrict__ pd_scores,
    const float* __restrict__ pd_bboxes,
    const float* __restrict__ anc_points,
    const float* __restrict__ gt_bboxes,
    const unsigned char* __restrict__ flags,
    int* __restrict__ out_fg,
    int* __restrict__ out_idx)
{
    __shared__ float s_box[NUM_G * 4];
    __shared__ float s_area[NUM_G];
    const int tid = threadIdx.x;
    if (tid < NUM_G) {
        float4 gb = ((const float4*)gt_bboxes)[tid];
        s_box[tid * 4 + 0] = gb.x;
        s_box[tid * 4 + 1] = gb.y;
        s_box[tid * 4 + 2] = gb.z;
        s_box[tid * 4 + 3] = gb.w;
        s_area[tid] = (gb.z - gb.x) * (gb.w - gb.y);
    }
    __syncthreads();

    const int a = blockIdx.x * 256 + tid;
    if (a >= NUM_A) return;

    float2 ap = ((const float2*)anc_points)[a];
    float4 pb = ((const float4*)pd_bboxes)[a];
    float parea = (pb.z - pb.x) * (pb.w - pb.y);
    float score = pd_scores[a];

    float best = -1.0f;
    int bidx = 0;
    for (int g = 0; g < NUM_G; ++g) {
        float m = metric_eval(ap.x, ap.y, pb.x, pb.y, pb.z, pb.w, parea, score,
                              s_box[g * 4 + 0], s_box[g * 4 + 1],
                              s_box[g * 4 + 2], s_box[g * 4 + 3], s_area[g]);
        if (m > best) { best = m; bidx = g; }   // strict > : first max
    }
    const int fg = flags[a] ? 1 : 0;
    out_fg[a]  = fg;
    out_idx[a] = fg ? bidx : 0;
}

extern "C" void kernel_launch(void* const* d_in, const int* in_sizes, int n_in,
                              void* d_out, int out_size, void* d_ws, size_t ws_size,
                              hipStream_t stream) {
    const float* pd_scores  = (const float*)d_in[0];   // (A,1) f32
    const float* pd_bboxes  = (const float*)d_in[1];   // (A,4) f32
    const float* anc_points = (const float*)d_in[2];   // (A,2) f32
    // d_in[3] = gt_labels (G,) int32 — unused (NUM_CLASSES==1 -> all 0)
    const float* gt_bboxes  = (const float*)d_in[4];   // (G,4) f32

    const int npairs = NUM_G * CHUNKS * TOPK;          // 20480
    float* pval = (float*)d_ws;
    int*   pidx = (int*)(pval + npairs);
    unsigned char* flags = (unsigned char*)(pidx + npairs);  // NUM_A bytes

    int* out32 = (int*)d_out;   // [fg_mask(A) | assigned_gt_idx(A)] as int32

    hipMemsetAsync(flags, 0, NUM_A, stream);   // capture-safe

    dim3 g1(CHUNKS, NGROUPS);
    topk_partial_kernel<<<g1, 256, 0, stream>>>(
        pd_scores, pd_bboxes, anc_points, gt_bboxes, pval, pidx);
    merge_scatter_kernel<<<1, 64, 0, stream>>>(pval, pidx, flags);
    assign_kernel<<<(NUM_A + 255) / 256, 256, 0, stream>>>(
        pd_scores, pd_bboxes, anc_points, gt_bboxes, flags,
        out32, out32 + NUM_A);
}

// Round 3
// 312.950 us; speedup vs baseline: 1.4147x; 1.4147x over previous
//
#include <hip/hip_runtime.h>

#define NUM_A    400000
#define NUM_G    64
#define TOPK     10
#define CHUNKS   32
#define CHUNK_SZ (NUM_A / CHUNKS)   // 12500
#define GGROUP   4                  // GTs per K1 block
#define NGROUPS  (NUM_G / GGROUP)   // 16

// top_k ordering: larger value first; ties -> lower anchor index first.
__device__ __forceinline__ bool better(float m1, int a1, float m2, int a2) {
    return (m1 > m2) || ((m1 == m2) && (a1 < a2));
}

__device__ __forceinline__ float metric_eval(
    float x, float y,
    float px1, float py1, float px2, float py2, float parea, float score,
    float gx1, float gy1, float gx2, float gy2, float garea)
{
    bool in_gt = (x >= gx1) && (x <= gx2) && (y >= gy1) && (y <= gy2);
    float ltx = fmaxf(px1, gx1);
    float lty = fmaxf(py1, gy1);
    float rbx = fminf(px2, gx2);
    float rby = fminf(py2, gy2);
    float w = fmaxf(rbx - ltx, 0.0f);
    float h = fmaxf(rby - lty, 0.0f);
    float inter = w * h;
    float iou = inter / (parea + garea - inter);   // denom >= 64 always
    float iou2 = iou * iou;
    float iou6 = iou2 * iou2 * iou2;
    float cls = in_gt ? score : 0.0f;
    return cls * iou6;
}

// K1: block = (chunk c, gt-group gg). Per-thread register top-10 (value,idx)
// per GT in group, then LDS tree merge. Output: sorted top-10 pairs per (g,c).
// NOTE: every loop touching tv[]/ti[] MUST be #pragma unroll — any dynamic
// index demotes the arrays to scratch (round-2: 639 MB of spill writes).
__global__ __launch_bounds__(256) void topk_partial_kernel(
    const float* __restrict__ pd_scores,
    const float* __restrict__ pd_bboxes,
    const float* __restrict__ anc_points,
    const float* __restrict__ gt_bboxes,
    float* __restrict__ pval,
    int*   __restrict__ pidx)
{
    const int c   = blockIdx.x;
    const int gg  = blockIdx.y;
    const int tid = threadIdx.x;
    const int g0  = gg * GGROUP;

    float gx1[GGROUP], gy1[GGROUP], gx2[GGROUP], gy2[GGROUP], ga[GGROUP];
#pragma unroll
    for (int j = 0; j < GGROUP; ++j) {
        float4 gb = ((const float4*)gt_bboxes)[g0 + j];
        gx1[j] = gb.x; gy1[j] = gb.y; gx2[j] = gb.z; gy2[j] = gb.w;
        ga[j] = (gb.z - gb.x) * (gb.w - gb.y);
    }

    float tv[GGROUP][TOPK];
    int   ti[GGROUP][TOPK];
#pragma unroll
    for (int j = 0; j < GGROUP; ++j)
#pragma unroll
        for (int k = 0; k < TOPK; ++k) { tv[j][k] = -1.0f; ti[j][k] = 0x7fffffff; }

    const int a0 = c * CHUNK_SZ, a1 = a0 + CHUNK_SZ;
    for (int a = a0 + tid; a < a1; a += 256) {
        float2 ap = ((const float2*)anc_points)[a];
        float4 pb = ((const float4*)pd_bboxes)[a];
        float parea = (pb.z - pb.x) * (pb.w - pb.y);
        float score = pd_scores[a];   // NUM_CLASSES == 1
#pragma unroll
        for (int j = 0; j < GGROUP; ++j) {
            float m = metric_eval(ap.x, ap.y, pb.x, pb.y, pb.z, pb.w, parea,
                                  score, gx1[j], gy1[j], gx2[j], gy2[j], ga[j]);
            // Within a thread, a strictly increases: on value ties the
            // incumbent (lower a) must win -> plain float > implements
            // top_k tie-break exactly. Keeps int compares off the hot path.
            if (m > tv[j][TOPK - 1]) {
#pragma unroll
                for (int k = TOPK - 1; k >= 1; --k) {
                    bool gp = m > tv[j][k - 1];
                    bool gc = m > tv[j][k];
                    tv[j][k] = gp ? tv[j][k - 1] : (gc ? m : tv[j][k]);
                    ti[j][k] = gp ? ti[j][k - 1] : (gc ? a : ti[j][k]);
                }
                if (m > tv[j][0]) { tv[j][0] = m; ti[j][0] = a; }
            }
        }
    }

    __shared__ float sv[256 * TOPK];
    __shared__ int   si[256 * TOPK];
#pragma unroll   // CRITICAL: keeps tv[j]/ti[j] statically indexed (VGPRs)
    for (int j = 0; j < GGROUP; ++j) {
        __syncthreads();   // protect LDS writes vs previous iteration's reads
#pragma unroll
        for (int k = 0; k < TOPK; ++k) {
            sv[tid * TOPK + k] = tv[j][k];
            si[tid * TOPK + k] = ti[j][k];
        }
        for (int off = 128; off >= 1; off >>= 1) {
            __syncthreads();
            if (tid < off) {
                const int rA = tid * TOPK, rB = (tid + off) * TOPK;
                float mv[TOPK]; int mi[TOPK];
                int ia = 0, ib = 0;
#pragma unroll
                for (int k = 0; k < TOPK; ++k) {     // ia,ib <= k <= 9: in range
                    float va = sv[rA + ia], vb = sv[rB + ib];
                    int   na = si[rA + ia], nb = si[rB + ib];
                    bool tA = better(va, na, vb, nb);
                    mv[k] = tA ? va : vb;
                    mi[k] = tA ? na : nb;
                    ia += tA ? 1 : 0;
                    ib += tA ? 0 : 1;
                }
#pragma unroll
                for (int k = 0; k < TOPK; ++k) { sv[rA + k] = mv[k]; si[rA + k] = mi[k]; }
            }
        }
        __syncthreads();
        if (tid < TOPK) {
            const int g = g0 + j;
            pval[(g * CHUNKS + c) * TOPK + tid] = sv[tid];
            pidx[(g * CHUNKS + c) * TOPK + tid] = si[tid];
        }
    }
}

// K2: thread g merges its 32 sorted lists (320 pairs) -> exact top-10 anchor
// ids for column g; marks flags[a]=1 for those with value > 0.
__global__ __launch_bounds__(64) void merge_scatter_kernel(
    const float* __restrict__ pval,
    const int*   __restrict__ pidx,
    unsigned char* __restrict__ flags)
{
    const int g = threadIdx.x;
    float tv[TOPK]; int ti[TOPK];
#pragma unroll
    for (int k = 0; k < TOPK; ++k) { tv[k] = -1.0f; ti[k] = 0x7fffffff; }
    const float* pv = pval + g * CHUNKS * TOPK;
    const int*   pi = pidx + g * CHUNKS * TOPK;
    for (int i = 0; i < CHUNKS * TOPK; ++i) {
        float m = pv[i];
        int   a = pi[i];
        if (better(m, a, tv[TOPK - 1], ti[TOPK - 1])) {
#pragma unroll
            for (int k = TOPK - 1; k >= 1; --k) {
                bool gp = better(m, a, tv[k - 1], ti[k - 1]);
                bool gc = better(m, a, tv[k],     ti[k]);
                tv[k] = gp ? tv[k - 1] : (gc ? m : tv[k]);
                ti[k] = gp ? ti[k - 1] : (gc ? a : ti[k]);
            }
            if (better(m, a, tv[0], ti[0])) { tv[0] = m; ti[0] = a; }
        }
    }
#pragma unroll
    for (int k = 0; k < TOPK; ++k)
        if (tv[k] > 0.0f) flags[ti[k]] = 1;   // same-value byte races benign
}

// K3: fg from flags (exact); idx = fg ? argmax_g metric : 0 (first-max).
__global__ __launch_bounds__(256) void assign_kernel(
    const float* __restrict__ pd_scores,
    const float* __restrict__ pd_bboxes,
    const float* __restrict__ anc_points,
    const float* __restrict__ gt_bboxes,
    const unsigned char* __restrict__ flags,
    int* __restrict__ out_fg,
    int* __restrict__ out_idx)
{
    __shared__ float s_box[NUM_G * 4];
    __shared__ float s_area[NUM_G];
    const int tid = threadIdx.x;
    if (tid < NUM_G) {
        float4 gb = ((const float4*)gt_bboxes)[tid];
        s_box[tid * 4 + 0] = gb.x;
        s_box[tid * 4 + 1] = gb.y;
        s_box[tid * 4 + 2] = gb.z;
        s_box[tid * 4 + 3] = gb.w;
        s_area[tid] = (gb.z - gb.x) * (gb.w - gb.y);
    }
    __syncthreads();

    const int a = blockIdx.x * 256 + tid;
    if (a >= NUM_A) return;

    float2 ap = ((const float2*)anc_points)[a];
    float4 pb = ((const float4*)pd_bboxes)[a];
    float parea = (pb.z - pb.x) * (pb.w - pb.y);
    float score = pd_scores[a];

    float best = -1.0f;
    int bidx = 0;
    for (int g = 0; g < NUM_G; ++g) {
        float m = metric_eval(ap.x, ap.y, pb.x, pb.y, pb.z, pb.w, parea, score,
                              s_box[g * 4 + 0], s_box[g * 4 + 1],
                              s_box[g * 4 + 2], s_box[g * 4 + 3], s_area[g]);
        if (m > best) { best = m; bidx = g; }   // strict > : first max
    }
    const int fg = flags[a] ? 1 : 0;
    out_fg[a]  = fg;
    out_idx[a] = fg ? bidx : 0;
}

extern "C" void kernel_launch(void* const* d_in, const int* in_sizes, int n_in,
                              void* d_out, int out_size, void* d_ws, size_t ws_size,
                              hipStream_t stream) {
    const float* pd_scores  = (const float*)d_in[0];   // (A,1) f32
    const float* pd_bboxes  = (const float*)d_in[1];   // (A,4) f32
    const float* anc_points = (const float*)d_in[2];   // (A,2) f32
    // d_in[3] = gt_labels (G,) int32 — unused (NUM_CLASSES==1 -> all 0)
    const float* gt_bboxes  = (const float*)d_in[4];   // (G,4) f32

    const int npairs = NUM_G * CHUNKS * TOPK;          // 20480
    float* pval = (float*)d_ws;
    int*   pidx = (int*)(pval + npairs);
    unsigned char* flags = (unsigned char*)(pidx + npairs);  // NUM_A bytes

    int* out32 = (int*)d_out;   // [fg_mask(A) | assigned_gt_idx(A)] as int32

    hipMemsetAsync(flags, 0, NUM_A, stream);   // capture-safe

    dim3 g1(CHUNKS, NGROUPS);
    topk_partial_kernel<<<g1, 256, 0, stream>>>(
        pd_scores, pd_bboxes, anc_points, gt_bboxes, pval, pidx);
    merge_scatter_kernel<<<1, 64, 0, stream>>>(pval, pidx, flags);
    assign_kernel<<<(NUM_A + 255) / 256, 256, 0, stream>>>(
        pd_scores, pd_bboxes, anc_points, gt_bboxes, flags,
        out32, out32 + NUM_A);
}

// Round 4
// 190.126 us; speedup vs baseline: 2.3285x; 1.6460x over previous
//
#include <hip/hip_runtime.h>

#define NUM_A    400000
#define NUM_G    64
#define TOPK     10
#define CHUNKS   32
#define CHUNK_SZ (NUM_A / CHUNKS)   // 12500
#define GGROUP   4                  // GTs per K1 block
#define NGROUPS  (NUM_G / GGROUP)   // 16

// top_k ordering: larger value first; ties -> lower anchor index first.
__device__ __forceinline__ bool better(float m1, int a1, float m2, int a2) {
    return (m1 > m2) || ((m1 == m2) && (a1 < a2));
}

__device__ __forceinline__ float metric_eval(
    float x, float y,
    float px1, float py1, float px2, float py2, float parea, float score,
    float gx1, float gy1, float gx2, float gy2, float garea)
{
    bool in_gt = (x >= gx1) && (x <= gx2) && (y >= gy1) && (y <= gy2);
    float ltx = fmaxf(px1, gx1);
    float lty = fmaxf(py1, gy1);
    float rbx = fminf(px2, gx2);
    float rby = fminf(py2, gy2);
    float w = fmaxf(rbx - ltx, 0.0f);
    float h = fmaxf(rby - lty, 0.0f);
    float inter = w * h;
    float iou = inter / (parea + garea - inter);   // denom >= 64 always
    float iou2 = iou * iou;
    float iou6 = iou2 * iou2 * iou2;
    float cls = in_gt ? score : 0.0f;
    return cls * iou6;
}

// K1: block = (chunk c, gt-group gg). Per-thread register top-10 (value,idx)
// per GT in group, then LDS tree merge. Output: sorted top-10 pairs per (g,c).
// NOTE: every loop touching tv[]/ti[] MUST be #pragma unroll — any dynamic
// index demotes the arrays to scratch (round-2: 639 MB of spill writes).
__global__ __launch_bounds__(256) void topk_partial_kernel(
    const float* __restrict__ pd_scores,
    const float* __restrict__ pd_bboxes,
    const float* __restrict__ anc_points,
    const float* __restrict__ gt_bboxes,
    float* __restrict__ pval,
    int*   __restrict__ pidx)
{
    const int c   = blockIdx.x;
    const int gg  = blockIdx.y;
    const int tid = threadIdx.x;
    const int g0  = gg * GGROUP;

    float gx1[GGROUP], gy1[GGROUP], gx2[GGROUP], gy2[GGROUP], ga[GGROUP];
#pragma unroll
    for (int j = 0; j < GGROUP; ++j) {
        float4 gb = ((const float4*)gt_bboxes)[g0 + j];
        gx1[j] = gb.x; gy1[j] = gb.y; gx2[j] = gb.z; gy2[j] = gb.w;
        ga[j] = (gb.z - gb.x) * (gb.w - gb.y);
    }

    float tv[GGROUP][TOPK];
    int   ti[GGROUP][TOPK];
#pragma unroll
    for (int j = 0; j < GGROUP; ++j)
#pragma unroll
        for (int k = 0; k < TOPK; ++k) { tv[j][k] = -1.0f; ti[j][k] = 0x7fffffff; }

    const int a0 = c * CHUNK_SZ, a1 = a0 + CHUNK_SZ;
    for (int a = a0 + tid; a < a1; a += 256) {
        float2 ap = ((const float2*)anc_points)[a];
        float4 pb = ((const float4*)pd_bboxes)[a];
        float parea = (pb.z - pb.x) * (pb.w - pb.y);
        float score = pd_scores[a];   // NUM_CLASSES == 1
#pragma unroll
        for (int j = 0; j < GGROUP; ++j) {
            float m = metric_eval(ap.x, ap.y, pb.x, pb.y, pb.z, pb.w, parea,
                                  score, gx1[j], gy1[j], gx2[j], gy2[j], ga[j]);
            // Within a thread, a strictly increases: on value ties the
            // incumbent (lower a) must win -> plain float > implements
            // top_k tie-break exactly. Keeps int compares off the hot path.
            if (m > tv[j][TOPK - 1]) {
#pragma unroll
                for (int k = TOPK - 1; k >= 1; --k) {
                    bool gp = m > tv[j][k - 1];
                    bool gc = m > tv[j][k];
                    tv[j][k] = gp ? tv[j][k - 1] : (gc ? m : tv[j][k]);
                    ti[j][k] = gp ? ti[j][k - 1] : (gc ? a : ti[j][k]);
                }
                if (m > tv[j][0]) { tv[j][0] = m; ti[j][0] = a; }
            }
        }
    }

    __shared__ float sv[256 * TOPK];
    __shared__ int   si[256 * TOPK];
#pragma unroll   // CRITICAL: keeps tv[j]/ti[j] statically indexed (VGPRs)
    for (int j = 0; j < GGROUP; ++j) {
        __syncthreads();   // protect LDS writes vs previous iteration's reads
#pragma unroll
        for (int k = 0; k < TOPK; ++k) {
            sv[tid * TOPK + k] = tv[j][k];
            si[tid * TOPK + k] = ti[j][k];
        }
        for (int off = 128; off >= 1; off >>= 1) {
            __syncthreads();
            if (tid < off) {
                const int rA = tid * TOPK, rB = (tid + off) * TOPK;
                float mv[TOPK]; int mi[TOPK];
                int ia = 0, ib = 0;
#pragma unroll
                for (int k = 0; k < TOPK; ++k) {     // ia,ib <= k <= 9: in range
                    float va = sv[rA + ia], vb = sv[rB + ib];
                    int   na = si[rA + ia], nb = si[rB + ib];
                    bool tA = better(va, na, vb, nb);
                    mv[k] = tA ? va : vb;
                    mi[k] = tA ? na : nb;
                    ia += tA ? 1 : 0;
                    ib += tA ? 0 : 1;
                }
#pragma unroll
                for (int k = 0; k < TOPK; ++k) { sv[rA + k] = mv[k]; si[rA + k] = mi[k]; }
            }
        }
        __syncthreads();
        if (tid < TOPK) {
            const int g = g0 + j;
            pval[(g * CHUNKS + c) * TOPK + tid] = sv[tid];
            pidx[(g * CHUNKS + c) * TOPK + tid] = si[tid];
        }
    }
}

// K2: one block per GT. 32 lanes load their chunk's sorted 10-list into LDS,
// 5-level tree merge -> exact top-10 anchor ids; set flags for value > 0.
// (Round-3: the serial 1-block version was 132 us — one wave eating ~990
// cycles/iter of global-load latency while 255 CUs idled.)
__global__ __launch_bounds__(64) void merge_scatter_kernel(
    const float* __restrict__ pval,
    const int*   __restrict__ pidx,
    unsigned char* __restrict__ flags)
{
    const int g   = blockIdx.x;
    const int tid = threadIdx.x;

    __shared__ float sv[CHUNKS * TOPK];
    __shared__ int   si[CHUNKS * TOPK];

    if (tid < CHUNKS) {
        const float* pv = pval + (g * CHUNKS + tid) * TOPK;
        const int*   pi = pidx + (g * CHUNKS + tid) * TOPK;
#pragma unroll
        for (int k = 0; k < TOPK; ++k) {
            sv[tid * TOPK + k] = pv[k];
            si[tid * TOPK + k] = pi[k];
        }
    }
    for (int off = CHUNKS / 2; off >= 1; off >>= 1) {
        __syncthreads();
        if (tid < off) {
            const int rA = tid * TOPK, rB = (tid + off) * TOPK;
            float mv[TOPK]; int mi[TOPK];
            int ia = 0, ib = 0;
#pragma unroll
            for (int k = 0; k < TOPK; ++k) {
                float va = sv[rA + ia], vb = sv[rB + ib];
                int   na = si[rA + ia], nb = si[rB + ib];
                bool tA = better(va, na, vb, nb);
                mv[k] = tA ? va : vb;
                mi[k] = tA ? na : nb;
                ia += tA ? 1 : 0;
                ib += tA ? 0 : 1;
            }
#pragma unroll
            for (int k = 0; k < TOPK; ++k) { sv[rA + k] = mv[k]; si[rA + k] = mi[k]; }
        }
    }
    __syncthreads();
    if (tid < TOPK) {
        float v = sv[tid];
        int   a = si[tid];
        if (v > 0.0f) flags[a] = 1;   // same-value byte races benign
    }
}

// K3: fg from flags (exact); idx = fg ? argmax_g metric : 0 (first-max).
__global__ __launch_bounds__(256) void assign_kernel(
    const float* __restrict__ pd_scores,
    const float* __restrict__ pd_bboxes,
    const float* __restrict__ anc_points,
    const float* __restrict__ gt_bboxes,
    const unsigned char* __restrict__ flags,
    int* __restrict__ out_fg,
    int* __restrict__ out_idx)
{
    __shared__ float s_box[NUM_G * 4];
    __shared__ float s_area[NUM_G];
    const int tid = threadIdx.x;
    if (tid < NUM_G) {
        float4 gb = ((const float4*)gt_bboxes)[tid];
        s_box[tid * 4 + 0] = gb.x;
        s_box[tid * 4 + 1] = gb.y;
        s_box[tid * 4 + 2] = gb.z;
        s_box[tid * 4 + 3] = gb.w;
        s_area[tid] = (gb.z - gb.x) * (gb.w - gb.y);
    }
    __syncthreads();

    const int a = blockIdx.x * 256 + tid;
    if (a >= NUM_A) return;

    float2 ap = ((const float2*)anc_points)[a];
    float4 pb = ((const float4*)pd_bboxes)[a];
    float parea = (pb.z - pb.x) * (pb.w - pb.y);
    float score = pd_scores[a];

    float best = -1.0f;
    int bidx = 0;
    for (int g = 0; g < NUM_G; ++g) {
        float m = metric_eval(ap.x, ap.y, pb.x, pb.y, pb.z, pb.w, parea, score,
                              s_box[g * 4 + 0], s_box[g * 4 + 1],
                              s_box[g * 4 + 2], s_box[g * 4 + 3], s_area[g]);
        if (m > best) { best = m; bidx = g; }   // strict > : first max
    }
    const int fg = flags[a] ? 1 : 0;
    out_fg[a]  = fg;
    out_idx[a] = fg ? bidx : 0;
}

extern "C" void kernel_launch(void* const* d_in, const int* in_sizes, int n_in,
                              void* d_out, int out_size, void* d_ws, size_t ws_size,
                              hipStream_t stream) {
    const float* pd_scores  = (const float*)d_in[0];   // (A,1) f32
    const float* pd_bboxes  = (const float*)d_in[1];   // (A,4) f32
    const float* anc_points = (const float*)d_in[2];   // (A,2) f32
    // d_in[3] = gt_labels (G,) int32 — unused (NUM_CLASSES==1 -> all 0)
    const float* gt_bboxes  = (const float*)d_in[4];   // (G,4) f32

    const int npairs = NUM_G * CHUNKS * TOPK;          // 20480
    float* pval = (float*)d_ws;
    int*   pidx = (int*)(pval + npairs);
    unsigned char* flags = (unsigned char*)(pidx + npairs);  // NUM_A bytes

    int* out32 = (int*)d_out;   // [fg_mask(A) | assigned_gt_idx(A)] as int32

    hipMemsetAsync(flags, 0, NUM_A, stream);   // capture-safe

    dim3 g1(CHUNKS, NGROUPS);
    topk_partial_kernel<<<g1, 256, 0, stream>>>(
        pd_scores, pd_bboxes, anc_points, gt_bboxes, pval, pidx);
    merge_scatter_kernel<<<NUM_G, 64, 0, stream>>>(pval, pidx, flags);
    assign_kernel<<<(NUM_A + 255) / 256, 256, 0, stream>>>(
        pd_scores, pd_bboxes, anc_points, gt_bboxes, flags,
        out32, out32 + NUM_A);
}

// Round 5
// 120.338 us; speedup vs baseline: 3.6789x; 1.5799x over previous
//
#include <hip/hip_runtime.h>

#define NUM_A    400000
#define NUM_G    64
#define TOPK     10
#define CHUNKS   64
#define CHUNK_SZ (NUM_A / CHUNKS)   // 6250
#define GGROUP   4                  // GTs per K1 block (= waves per block)
#define NGROUPS  (NUM_G / GGROUP)   // 16
#define CAP      768                // per-GT candidate capacity per chunk
                                    // (max possible E[in-box] = 6250*4% = 250)

// top_k ordering: larger value first; ties -> lower anchor index first.
__device__ __forceinline__ bool better(float m1, int a1, float m2, int a2) {
    return (m1 > m2) || ((m1 == m2) && (a1 < a2));
}

// IoU-metric for a pair KNOWN to be in-box (or gated by caller). Arithmetic
// order identical to rounds 2-4 (which passed absmax=0 vs numpy).
__device__ __forceinline__ float iou_metric(
    float px1, float py1, float px2, float py2, float parea, float score,
    float gx1, float gy1, float gx2, float gy2, float garea)
{
    float ltx = fmaxf(px1, gx1);
    float lty = fmaxf(py1, gy1);
    float rbx = fminf(px2, gx2);
    float rby = fminf(py2, gy2);
    float w = fmaxf(rbx - ltx, 0.0f);
    float h = fmaxf(rby - lty, 0.0f);
    float inter = w * h;
    float iou = inter / (parea + garea - inter);   // denom >= 64 always
    float iou2 = iou * iou;
    float iou6 = iou2 * iou2 * iou2;
    return score * iou6;
}

// K1: block = (chunk c, gt-group gg), 4 waves.
// Phase A: in-box test only (loads just anc_points, 2 anchors per float4),
//          append hits to per-GT LDS candidate lists (~1.3% of pairs).
// Phase B: wave j evaluates GT j's candidates (full metric + exact
//          (value,idx) top-10 insert), then LDS tree-merge over 64 lanes.
__global__ __launch_bounds__(256) void topk_partial_kernel(
    const float* __restrict__ pd_scores,
    const float* __restrict__ pd_bboxes,
    const float* __restrict__ anc_points,
    const float* __restrict__ gt_bboxes,
    float* __restrict__ pval,
    int*   __restrict__ pidx)
{
    const int c   = blockIdx.x;
    const int gg  = blockIdx.y;
    const int tid = threadIdx.x;
    const int g0  = gg * GGROUP;

    __shared__ int   s_cnt[GGROUP];
    __shared__ int   s_cand[GGROUP][CAP];
    __shared__ float s_mv[GGROUP * 64 * TOPK];
    __shared__ int   s_mi[GGROUP * 64 * TOPK];

    if (tid < GGROUP) s_cnt[tid] = 0;

    float gx1[GGROUP], gy1[GGROUP], gx2[GGROUP], gy2[GGROUP];
#pragma unroll
    for (int j = 0; j < GGROUP; ++j) {
        float4 gb = ((const float4*)gt_bboxes)[g0 + j];
        gx1[j] = gb.x; gy1[j] = gb.y; gx2[j] = gb.z; gy2[j] = gb.w;
    }
    __syncthreads();

    // ---- Phase A: candidate collection ----
    const int p0 = c * (CHUNK_SZ / 2);          // float4 = 2 anchors
    const int p1 = p0 + CHUNK_SZ / 2;
    for (int p = p0 + tid; p < p1; p += 256) {
        float4 aq = ((const float4*)anc_points)[p];
        const int a2 = 2 * p;
#pragma unroll
        for (int j = 0; j < GGROUP; ++j) {
            bool in0 = (aq.x >= gx1[j]) && (aq.x <= gx2[j]) &&
                       (aq.y >= gy1[j]) && (aq.y <= gy2[j]);
            bool in1 = (aq.z >= gx1[j]) && (aq.z <= gx2[j]) &&
                       (aq.w >= gy1[j]) && (aq.w <= gy2[j]);
            if (in0) { int q = atomicAdd(&s_cnt[j], 1); if (q < CAP) s_cand[j][q] = a2; }
            if (in1) { int q = atomicAdd(&s_cnt[j], 1); if (q < CAP) s_cand[j][q] = a2 + 1; }
        }
    }
    __syncthreads();

    // ---- Phase B: per-wave candidate evaluation ----
    const int wj   = tid >> 6;     // wave = GT within group
    const int lane = tid & 63;

    float4 gb = ((const float4*)gt_bboxes)[g0 + wj];   // wave-uniform
    const float garea = (gb.z - gb.x) * (gb.w - gb.y);
    const int n = min(s_cnt[wj], CAP);

    float tv[TOPK]; int ti[TOPK];
#pragma unroll
    for (int k = 0; k < TOPK; ++k) { tv[k] = 0.0f; ti[k] = 0x7fffffff; }

    for (int i = lane; i < n; i += 64) {
        const int a = s_cand[wj][i];
        float4 pb = ((const float4*)pd_bboxes)[a];
        float sc = pd_scores[a];
        float parea = (pb.z - pb.x) * (pb.w - pb.y);
        float m = iou_metric(pb.x, pb.y, pb.z, pb.w, parea, sc,
                             gb.x, gb.y, gb.z, gb.w, garea);
        // candidate order is atomic-append order -> need full (v,idx) compare
        if (better(m, a, tv[TOPK - 1], ti[TOPK - 1])) {
#pragma unroll
            for (int k = TOPK - 1; k >= 1; --k) {
                bool gp = better(m, a, tv[k - 1], ti[k - 1]);
                bool gc = better(m, a, tv[k],     ti[k]);
                tv[k] = gp ? tv[k - 1] : (gc ? m : tv[k]);
                ti[k] = gp ? ti[k - 1] : (gc ? a : ti[k]);
            }
            if (better(m, a, tv[0], ti[0])) { tv[0] = m; ti[0] = a; }
        }
    }

    // ---- tree merge: 64 lane-lists -> 1 per wave ----
#pragma unroll
    for (int k = 0; k < TOPK; ++k) {
        s_mv[(wj * 64 + lane) * TOPK + k] = tv[k];
        s_mi[(wj * 64 + lane) * TOPK + k] = ti[k];
    }
    for (int off = 32; off >= 1; off >>= 1) {
        __syncthreads();
        if (lane < off) {
            const int rA = (wj * 64 + lane) * TOPK;
            const int rB = (wj * 64 + lane + off) * TOPK;
            float mv[TOPK]; int mi[TOPK];
            int ia = 0, ib = 0;
#pragma unroll
            for (int k = 0; k < TOPK; ++k) {   // ia,ib <= k <= 9: in range
                float va = s_mv[rA + ia], vb = s_mv[rB + ib];
                int   na = s_mi[rA + ia], nb = s_mi[rB + ib];
                bool tA = better(va, na, vb, nb);
                mv[k] = tA ? va : vb;
                mi[k] = tA ? na : nb;
                ia += tA ? 1 : 0;
                ib += tA ? 0 : 1;
            }
#pragma unroll
            for (int k = 0; k < TOPK; ++k) { s_mv[rA + k] = mv[k]; s_mi[rA + k] = mi[k]; }
        }
    }
    __syncthreads();
    if (lane < TOPK) {
        const int g = g0 + wj;
        pval[(g * CHUNKS + c) * TOPK + lane] = s_mv[wj * 64 * TOPK + lane];
        pidx[(g * CHUNKS + c) * TOPK + lane] = s_mi[wj * 64 * TOPK + lane];
    }
}

// K2: one block per GT. 64 lanes load their chunk's sorted 10-list into LDS,
// 6-level tree merge -> exact top-10; set out_fg[a]=1 for value > 0.
__global__ __launch_bounds__(64) void merge_scatter_kernel(
    const float* __restrict__ pval,
    const int*   __restrict__ pidx,
    int* __restrict__ out_fg)
{
    const int g   = blockIdx.x;
    const int tid = threadIdx.x;

    __shared__ float sv[CHUNKS * TOPK];
    __shared__ int   si[CHUNKS * TOPK];

    const float* pv = pval + (g * CHUNKS + tid) * TOPK;
    const int*   pi = pidx + (g * CHUNKS + tid) * TOPK;
#pragma unroll
    for (int k = 0; k < TOPK; ++k) {
        sv[tid * TOPK + k] = pv[k];
        si[tid * TOPK + k] = pi[k];
    }
    for (int off = CHUNKS / 2; off >= 1; off >>= 1) {
        __syncthreads();
        if (tid < off) {
            const int rA = tid * TOPK, rB = (tid + off) * TOPK;
            float mv[TOPK]; int mi[TOPK];
            int ia = 0, ib = 0;
#pragma unroll
            for (int k = 0; k < TOPK; ++k) {
                float va = sv[rA + ia], vb = sv[rB + ib];
                int   na = si[rA + ia], nb = si[rB + ib];
                bool tA = better(va, na, vb, nb);
                mv[k] = tA ? va : vb;
                mi[k] = tA ? na : nb;
                ia += tA ? 1 : 0;
                ib += tA ? 0 : 1;
            }
#pragma unroll
            for (int k = 0; k < TOPK; ++k) { sv[rA + k] = mv[k]; si[rA + k] = mi[k]; }
        }
    }
    __syncthreads();
    if (tid < TOPK) {
        if (sv[tid] > 0.0f) out_fg[si[tid]] = 1;   // same-value races benign
    }
}

// K3: per-anchor argmax. Build 64-bit in-box mask (GT boxes via uniform
// scalar loads), then evaluate the metric only on set bits (~0.8 avg).
__global__ __launch_bounds__(256) void argmax_kernel(
    const float* __restrict__ pd_scores,
    const float* __restrict__ pd_bboxes,
    const float* __restrict__ anc_points,
    const float* __restrict__ gt_bboxes,
    const int* __restrict__ fg_in,
    int* __restrict__ out_idx)
{
    __shared__ float4 s_gt[NUM_G];
    __shared__ float  s_ga[NUM_G];
    const int tid = threadIdx.x;
    if (tid < NUM_G) {
        float4 gb = ((const float4*)gt_bboxes)[tid];
        s_gt[tid] = gb;
        s_ga[tid] = (gb.z - gb.x) * (gb.w - gb.y);
    }
    __syncthreads();

    const int a = blockIdx.x * 256 + tid;
    if (a >= NUM_A) return;

    float2 ap = ((const float2*)anc_points)[a];

    unsigned long long mask = 0ull;
    for (int g = 0; g < NUM_G; ++g) {
        float4 gb = ((const float4*)gt_bboxes)[g];   // uniform -> s_load path
        bool in = (ap.x >= gb.x) && (ap.x <= gb.z) &&
                  (ap.y >= gb.y) && (ap.y <= gb.w);
        mask |= ((unsigned long long)(in ? 1u : 0u)) << g;
    }

    float best = 0.0f;   // zeros never win -> bidx stays 0, matching argmax
    int bidx = 0;
    if (mask) {
        float4 pb = ((const float4*)pd_bboxes)[a];
        float sc = pd_scores[a];
        float parea = (pb.z - pb.x) * (pb.w - pb.y);
        do {
            const int g = __ffsll(mask) - 1;
            mask &= mask - 1ull;
            float4 gb = s_gt[g];                     // lane-varying -> LDS
            float m = iou_metric(pb.x, pb.y, pb.z, pb.w, parea, sc,
                                 gb.x, gb.y, gb.z, gb.w, s_ga[g]);
            if (m > best) { best = m; bidx = g; }    // strict > : first max
        } while (mask);
    }
    const int fg = fg_in[a];
    out_idx[a] = fg ? bidx : 0;
}

extern "C" void kernel_launch(void* const* d_in, const int* in_sizes, int n_in,
                              void* d_out, int out_size, void* d_ws, size_t ws_size,
                              hipStream_t stream) {
    const float* pd_scores  = (const float*)d_in[0];   // (A,1) f32
    const float* pd_bboxes  = (const float*)d_in[1];   // (A,4) f32
    const float* anc_points = (const float*)d_in[2];   // (A,2) f32
    // d_in[3] = gt_labels (G,) int32 — unused (NUM_CLASSES==1 -> all 0)
    const float* gt_bboxes  = (const float*)d_in[4];   // (G,4) f32

    const int npairs = NUM_G * CHUNKS * TOPK;          // 40960
    float* pval = (float*)d_ws;                        // 160 KB
    int*   pidx = (int*)(pval + npairs);               // 160 KB (ws total 320 KB)

    int* out_fg  = (int*)d_out;            // fg flags live directly in output
    int* out_idx = out_fg + NUM_A;

    hipMemsetAsync(out_fg, 0, NUM_A * sizeof(int), stream);   // capture-safe

    dim3 g1(CHUNKS, NGROUPS);
    topk_partial_kernel<<<g1, 256, 0, stream>>>(
        pd_scores, pd_bboxes, anc_points, gt_bboxes, pval, pidx);
    merge_scatter_kernel<<<NUM_G, 64, 0, stream>>>(pval, pidx, out_fg);
    argmax_kernel<<<(NUM_A + 255) / 256, 256, 0, stream>>>(
        pd_scores, pd_bboxes, anc_points, gt_bboxes, out_fg, out_idx);
}

// Round 6
// 112.129 us; speedup vs baseline: 3.9483x; 1.0732x over previous
//
#include <hip/hip_runtime.h>

#define NUM_A    400000
#define NUM_G    64
#define TOPK     10
#define CHUNKS   64
#define CHUNK_SZ (NUM_A / CHUNKS)   // 6250
#define GGROUP   4                  // GTs per K1 block (= waves per block)
#define NGROUPS  (NUM_G / GGROUP)   // 16
#define CAP      768                // per-GT candidate cap per chunk
                                    // (mean in-box <= 250, SD ~15 -> 33 SD margin)

// top_k ordering: larger value first; ties -> lower anchor index first.
__device__ __forceinline__ bool better(float m1, int a1, float m2, int a2) {
    return (m1 > m2) || ((m1 == m2) && (a1 < a2));
}

// IoU-metric; arithmetic order identical to rounds 2-5 (absmax=0 vs numpy).
__device__ __forceinline__ float iou_metric(
    float px1, float py1, float px2, float py2, float parea, float score,
    float gx1, float gy1, float gx2, float gy2, float garea)
{
    float ltx = fmaxf(px1, gx1);
    float lty = fmaxf(py1, gy1);
    float rbx = fminf(px2, gx2);
    float rby = fminf(py2, gy2);
    float w = fmaxf(rbx - ltx, 0.0f);
    float h = fmaxf(rby - lty, 0.0f);
    float inter = w * h;
    float iou = inter / (parea + garea - inter);   // denom >= 64 always
    float iou2 = iou * iou;
    float iou6 = iou2 * iou2 * iou2;
    return score * iou6;
}

// K1: block = (chunk c, gt-group gg), 4 waves.
// Phase A: in-box test only; append hits to per-GT LDS candidate lists.
// Phase B: wave j evaluates GT j's candidates, then 64-lane LDS tree-merge.
__global__ __launch_bounds__(256) void topk_partial_kernel(
    const float* __restrict__ pd_scores,
    const float* __restrict__ pd_bboxes,
    const float* __restrict__ anc_points,
    const float* __restrict__ gt_bboxes,
    float* __restrict__ pval,
    int*   __restrict__ pidx)
{
    const int c   = blockIdx.x;
    const int gg  = blockIdx.y;
    const int tid = threadIdx.x;
    const int g0  = gg * GGROUP;

    __shared__ int   s_cnt[GGROUP];
    __shared__ int   s_cand[GGROUP][CAP];
    __shared__ float s_mv[GGROUP * 64 * TOPK];
    __shared__ int   s_mi[GGROUP * 64 * TOPK];

    if (tid < GGROUP) s_cnt[tid] = 0;

    float gx1[GGROUP], gy1[GGROUP], gx2[GGROUP], gy2[GGROUP];
#pragma unroll
    for (int j = 0; j < GGROUP; ++j) {
        float4 gb = ((const float4*)gt_bboxes)[g0 + j];
        gx1[j] = gb.x; gy1[j] = gb.y; gx2[j] = gb.z; gy2[j] = gb.w;
    }
    __syncthreads();

    // ---- Phase A: candidate collection ----
    const int p0 = c * (CHUNK_SZ / 2);          // float4 = 2 anchors
    const int p1 = p0 + CHUNK_SZ / 2;
    for (int p = p0 + tid; p < p1; p += 256) {
        float4 aq = ((const float4*)anc_points)[p];
        const int a2 = 2 * p;
#pragma unroll
        for (int j = 0; j < GGROUP; ++j) {
            bool in0 = (aq.x >= gx1[j]) && (aq.x <= gx2[j]) &&
                       (aq.y >= gy1[j]) && (aq.y <= gy2[j]);
            bool in1 = (aq.z >= gx1[j]) && (aq.z <= gx2[j]) &&
                       (aq.w >= gy1[j]) && (aq.w <= gy2[j]);
            if (in0) { int q = atomicAdd(&s_cnt[j], 1); if (q < CAP) s_cand[j][q] = a2; }
            if (in1) { int q = atomicAdd(&s_cnt[j], 1); if (q < CAP) s_cand[j][q] = a2 + 1; }
        }
    }
    __syncthreads();

    // ---- Phase B: per-wave candidate evaluation ----
    const int wj   = tid >> 6;     // wave = GT within group
    const int lane = tid & 63;

    float4 gb = ((const float4*)gt_bboxes)[g0 + wj];   // wave-uniform
    const float garea = (gb.z - gb.x) * (gb.w - gb.y);
    const int n = min(s_cnt[wj], CAP);

    float tv[TOPK]; int ti[TOPK];
#pragma unroll
    for (int k = 0; k < TOPK; ++k) { tv[k] = 0.0f; ti[k] = 0x7fffffff; }

    for (int i = lane; i < n; i += 64) {
        const int a = s_cand[wj][i];
        float4 pb = ((const float4*)pd_bboxes)[a];
        float sc = pd_scores[a];
        float parea = (pb.z - pb.x) * (pb.w - pb.y);
        float m = iou_metric(pb.x, pb.y, pb.z, pb.w, parea, sc,
                             gb.x, gb.y, gb.z, gb.w, garea);
        // candidate order is atomic-append order -> need full (v,idx) compare
        if (better(m, a, tv[TOPK - 1], ti[TOPK - 1])) {
#pragma unroll
            for (int k = TOPK - 1; k >= 1; --k) {
                bool gp = better(m, a, tv[k - 1], ti[k - 1]);
                bool gc = better(m, a, tv[k],     ti[k]);
                tv[k] = gp ? tv[k - 1] : (gc ? m : tv[k]);
                ti[k] = gp ? ti[k - 1] : (gc ? a : ti[k]);
            }
            if (better(m, a, tv[0], ti[0])) { tv[0] = m; ti[0] = a; }
        }
    }

    // ---- tree merge: 64 lane-lists -> 1 per wave ----
#pragma unroll
    for (int k = 0; k < TOPK; ++k) {
        s_mv[(wj * 64 + lane) * TOPK + k] = tv[k];
        s_mi[(wj * 64 + lane) * TOPK + k] = ti[k];
    }
    for (int off = 32; off >= 1; off >>= 1) {
        __syncthreads();
        if (lane < off) {
            const int rA = (wj * 64 + lane) * TOPK;
            const int rB = (wj * 64 + lane + off) * TOPK;
            float mv[TOPK]; int mi[TOPK];
            int ia = 0, ib = 0;
#pragma unroll
            for (int k = 0; k < TOPK; ++k) {   // ia,ib <= k <= 9: in range
                float va = s_mv[rA + ia], vb = s_mv[rB + ib];
                int   na = s_mi[rA + ia], nb = s_mi[rB + ib];
                bool tA = better(va, na, vb, nb);
                mv[k] = tA ? va : vb;
                mi[k] = tA ? na : nb;
                ia += tA ? 1 : 0;
                ib += tA ? 0 : 1;
            }
#pragma unroll
            for (int k = 0; k < TOPK; ++k) { s_mv[rA + k] = mv[k]; s_mi[rA + k] = mi[k]; }
        }
    }
    __syncthreads();
    if (lane < TOPK) {
        const int g = g0 + wj;
        pval[(g * CHUNKS + c) * TOPK + lane] = s_mv[wj * 64 * TOPK + lane];
        pidx[(g * CHUNKS + c) * TOPK + lane] = s_mi[wj * 64 * TOPK + lane];
    }
}

// K2: one block per GT. 64 lanes load their chunk's sorted 10-list into LDS,
// 6-level tree merge -> exact top-10. Winners (value>0): set out_fg[a]=1 and
// record anchor in win_slots[g*10+k]; losers record -1. All 640 slots written.
__global__ __launch_bounds__(64) void merge_scatter_kernel(
    const float* __restrict__ pval,
    const int*   __restrict__ pidx,
    int* __restrict__ out_fg,
    int* __restrict__ win_slots)
{
    const int g   = blockIdx.x;
    const int tid = threadIdx.x;

    __shared__ float sv[CHUNKS * TOPK];
    __shared__ int   si[CHUNKS * TOPK];

    const float* pv = pval + (g * CHUNKS + tid) * TOPK;
    const int*   pi = pidx + (g * CHUNKS + tid) * TOPK;
#pragma unroll
    for (int k = 0; k < TOPK; ++k) {
        sv[tid * TOPK + k] = pv[k];
        si[tid * TOPK + k] = pi[k];
    }
    for (int off = CHUNKS / 2; off >= 1; off >>= 1) {
        __syncthreads();
        if (tid < off) {
            const int rA = tid * TOPK, rB = (tid + off) * TOPK;
            float mv[TOPK]; int mi[TOPK];
            int ia = 0, ib = 0;
#pragma unroll
            for (int k = 0; k < TOPK; ++k) {
                float va = sv[rA + ia], vb = sv[rB + ib];
                int   na = si[rA + ia], nb = si[rB + ib];
                bool tA = better(va, na, vb, nb);
                mv[k] = tA ? va : vb;
                mi[k] = tA ? na : nb;
                ia += tA ? 1 : 0;
                ib += tA ? 0 : 1;
            }
#pragma unroll
            for (int k = 0; k < TOPK; ++k) { sv[rA + k] = mv[k]; si[rA + k] = mi[k]; }
        }
    }
    __syncthreads();
    if (tid < TOPK) {
        const bool win = sv[tid] > 0.0f;
        const int  a   = si[tid];
        if (win) out_fg[a] = 1;                  // same-value races benign
        win_slots[g * TOPK + tid] = win ? a : -1;
    }
}

// K4: argmax ONLY for winner anchors (<=640 of 400k; out_idx pre-zeroed).
// Duplicate anchors across GT columns compute identical values — benign race.
__global__ __launch_bounds__(64) void argmax_flagged_kernel(
    const float* __restrict__ pd_scores,
    const float* __restrict__ pd_bboxes,
    const float* __restrict__ anc_points,
    const float* __restrict__ gt_bboxes,
    const int* __restrict__ win_slots,
    int* __restrict__ out_idx)
{
    __shared__ float4 s_gt[NUM_G];
    __shared__ float  s_ga[NUM_G];
    const int tid = threadIdx.x;
    {   // blockDim == NUM_G == 64
        float4 gb = ((const float4*)gt_bboxes)[tid];
        s_gt[tid] = gb;
        s_ga[tid] = (gb.z - gb.x) * (gb.w - gb.y);
    }
    __syncthreads();

    const int a = win_slots[blockIdx.x * 64 + tid];
    if (a < 0) return;

    float2 ap = ((const float2*)anc_points)[a];
    float4 pb = ((const float4*)pd_bboxes)[a];
    float sc = pd_scores[a];
    float parea = (pb.z - pb.x) * (pb.w - pb.y);

    float best = 0.0f;   // zeros never win -> bidx stays 0, matching argmax
    int bidx = 0;
    for (int g = 0; g < NUM_G; ++g) {
        float4 gb = s_gt[g];
        bool in = (ap.x >= gb.x) && (ap.x <= gb.z) &&
                  (ap.y >= gb.y) && (ap.y <= gb.w);
        float m = iou_metric(pb.x, pb.y, pb.z, pb.w, parea,
                             in ? sc : 0.0f,      // cls gate, exact-0 when out
                             gb.x, gb.y, gb.z, gb.w, s_ga[g]);
        if (m > best) { best = m; bidx = g; }     // strict > : first max
    }
    out_idx[a] = bidx;
}

extern "C" void kernel_launch(void* const* d_in, const int* in_sizes, int n_in,
                              void* d_out, int out_size, void* d_ws, size_t ws_size,
                              hipStream_t stream) {
    const float* pd_scores  = (const float*)d_in[0];   // (A,1) f32
    const float* pd_bboxes  = (const float*)d_in[1];   // (A,4) f32
    const float* anc_points = (const float*)d_in[2];   // (A,2) f32
    // d_in[3] = gt_labels (G,) int32 — unused (NUM_CLASSES==1 -> all 0)
    const float* gt_bboxes  = (const float*)d_in[4];   // (G,4) f32

    const int npairs = NUM_G * CHUNKS * TOPK;          // 40960
    float* pval      = (float*)d_ws;                   // 160 KB
    int*   pidx      = (int*)(pval + npairs);          // 160 KB
    int*   win_slots = (int*)(pidx + npairs);          // 2.5 KB

    int* out_fg  = (int*)d_out;            // [fg(A) | idx(A)] as int32
    int* out_idx = out_fg + NUM_A;

    // zero BOTH output halves: non-winners get fg=0, idx=0
    hipMemsetAsync(d_out, 0, 2 * NUM_A * sizeof(int), stream);

    dim3 g1(CHUNKS, NGROUPS);
    topk_partial_kernel<<<g1, 256, 0, stream>>>(
        pd_scores, pd_bboxes, anc_points, gt_bboxes, pval, pidx);
    merge_scatter_kernel<<<NUM_G, 64, 0, stream>>>(pval, pidx, out_fg, win_slots);
    argmax_flagged_kernel<<<NUM_G * TOPK / 64, 64, 0, stream>>>(
        pd_scores, pd_bboxes, anc_points, gt_bboxes, win_slots, out_idx);
}

// Round 7
// 103.890 us; speedup vs baseline: 4.2614x; 1.0793x over previous
//
#include <hip/hip_runtime.h>

#define NUM_A    400000
#define NUM_G    64
#define TOPK     10
#define CHUNKS   64
#define CHUNK_SZ (NUM_A / CHUNKS)   // 6250
#define GGROUP   4                  // GTs per K1 block (= waves per block)
#define NGROUPS  (NUM_G / GGROUP)   // 16
#define CAP      768                // per-GT candidate cap per chunk
                                    // (mean in-box <= 250, SD ~15 -> 33 SD margin)
#define SENT_I   0x7fffffff

// top_k ordering: larger value first; ties -> lower anchor index first.
// Sentinel (0.0f, SENT_I) sorts after every real candidate (real zero-metric
// candidates have a < SENT_I).
__device__ __forceinline__ bool better(float m1, int a1, float m2, int a2) {
    return (m1 > m2) || ((m1 == m2) && (a1 < a2));
}

// IoU-metric; arithmetic order identical to rounds 2-6 (absmax=0 vs numpy).
__device__ __forceinline__ float iou_metric(
    float px1, float py1, float px2, float py2, float parea, float score,
    float gx1, float gy1, float gx2, float gy2, float garea)
{
    float ltx = fmaxf(px1, gx1);
    float lty = fmaxf(py1, gy1);
    float rbx = fminf(px2, gx2);
    float rby = fminf(py2, gy2);
    float w = fmaxf(rbx - ltx, 0.0f);
    float h = fmaxf(rby - lty, 0.0f);
    float inter = w * h;
    float iou = inter / (parea + garea - inter);   // denom >= 64 always
    float iou2 = iou * iou;
    float iou6 = iou2 * iou2 * iou2;
    return score * iou6;
}

// Wave-wide (64-lane) butterfly max of (value, anchor) under better().
__device__ __forceinline__ void wave_max_pair(float& bv, int& bi) {
#pragma unroll
    for (int s = 1; s < 64; s <<= 1) {
        float ov = __shfl_xor(bv, s, 64);
        int   oi = __shfl_xor(bi, s, 64);
        if (better(ov, oi, bv, bi)) { bv = ov; bi = oi; }
    }
}

// K1: block = (chunk c, gt-group gg), 4 waves.
// Phase A: in-box test only; append hits to per-GT LDS candidate lists.
// Phase B: wave j evaluates GT j's candidates into per-lane sorted top-10,
// then 10 rounds of wave-butterfly selection (register-only; replaces the
// round-6 LDS tree merge whose serial ds_read chain was the critical path).
__global__ __launch_bounds__(256) void topk_partial_kernel(
    const float* __restrict__ pd_scores,
    const float* __restrict__ pd_bboxes,
    const float* __restrict__ anc_points,
    const float* __restrict__ gt_bboxes,
    float* __restrict__ pval,
    int*   __restrict__ pidx)
{
    const int c   = blockIdx.x;
    const int gg  = blockIdx.y;
    const int tid = threadIdx.x;
    const int g0  = gg * GGROUP;

    __shared__ int s_cnt[GGROUP];
    __shared__ int s_cand[GGROUP][CAP];

    if (tid < GGROUP) s_cnt[tid] = 0;

    float gx1[GGROUP], gy1[GGROUP], gx2[GGROUP], gy2[GGROUP];
#pragma unroll
    for (int j = 0; j < GGROUP; ++j) {
        float4 gb = ((const float4*)gt_bboxes)[g0 + j];
        gx1[j] = gb.x; gy1[j] = gb.y; gx2[j] = gb.z; gy2[j] = gb.w;
    }
    __syncthreads();

    // ---- Phase A: candidate collection ----
    const int p0 = c * (CHUNK_SZ / 2);          // float4 = 2 anchors
    const int p1 = p0 + CHUNK_SZ / 2;
    for (int p = p0 + tid; p < p1; p += 256) {
        float4 aq = ((const float4*)anc_points)[p];
        const int a2 = 2 * p;
#pragma unroll
        for (int j = 0; j < GGROUP; ++j) {
            bool in0 = (aq.x >= gx1[j]) && (aq.x <= gx2[j]) &&
                       (aq.y >= gy1[j]) && (aq.y <= gy2[j]);
            bool in1 = (aq.z >= gx1[j]) && (aq.z <= gx2[j]) &&
                       (aq.w >= gy1[j]) && (aq.w <= gy2[j]);
            if (in0) { int q = atomicAdd(&s_cnt[j], 1); if (q < CAP) s_cand[j][q] = a2; }
            if (in1) { int q = atomicAdd(&s_cnt[j], 1); if (q < CAP) s_cand[j][q] = a2 + 1; }
        }
    }
    __syncthreads();

    // ---- Phase B: per-wave candidate evaluation ----
    const int wj   = tid >> 6;     // wave = GT within group
    const int lane = tid & 63;

    float4 gb = ((const float4*)gt_bboxes)[g0 + wj];   // wave-uniform
    const float garea = (gb.z - gb.x) * (gb.w - gb.y);
    const int n = min(s_cnt[wj], CAP);

    float tv[TOPK]; int ti[TOPK];
#pragma unroll
    for (int k = 0; k < TOPK; ++k) { tv[k] = 0.0f; ti[k] = SENT_I; }

    for (int i = lane; i < n; i += 64) {
        const int a = s_cand[wj][i];
        float4 pb = ((const float4*)pd_bboxes)[a];
        float sc = pd_scores[a];
        float parea = (pb.z - pb.x) * (pb.w - pb.y);
        float m = iou_metric(pb.x, pb.y, pb.z, pb.w, parea, sc,
                             gb.x, gb.y, gb.z, gb.w, garea);
        // candidate order is atomic-append order -> need full (v,idx) compare
        if (better(m, a, tv[TOPK - 1], ti[TOPK - 1])) {
#pragma unroll
            for (int k = TOPK - 1; k >= 1; --k) {
                bool gp = better(m, a, tv[k - 1], ti[k - 1]);
                bool gc = better(m, a, tv[k],     ti[k]);
                tv[k] = gp ? tv[k - 1] : (gc ? m : tv[k]);
                ti[k] = gp ? ti[k - 1] : (gc ? a : ti[k]);
            }
            if (better(m, a, tv[0], ti[0])) { tv[0] = m; ti[0] = a; }
        }
    }

    // ---- 10-round wave selection: 64 sorted lists -> global top-10 ----
    float outv = 0.0f; int outi = SENT_I;
#pragma unroll
    for (int k = 0; k < TOPK; ++k) {
        float bv = tv[0]; int bi = ti[0];
        wave_max_pair(bv, bi);
        // owner lane (unique real anchor id; sentinel-shift is harmless) pops
        bool win = (ti[0] == bi);
#pragma unroll
        for (int j = 0; j < TOPK - 1; ++j) {
            tv[j] = win ? tv[j + 1] : tv[j];
            ti[j] = win ? ti[j + 1] : ti[j];
        }
        if (win) { tv[TOPK - 1] = 0.0f; ti[TOPK - 1] = SENT_I; }
        if (lane == k) { outv = bv; outi = bi; }
    }
    if (lane < TOPK) {
        const int g = g0 + wj;
        pval[(g * CHUNKS + c) * TOPK + lane] = outv;
        pidx[(g * CHUNKS + c) * TOPK + lane] = outi;
    }
}

// K2 (fused with old K4): one block (one wave) per GT. Lane t holds chunk t's
// sorted 10-list; 10 rounds of wave selection give the exact top-10. For each
// positive winner (wave-uniform), all 64 lanes compute that anchor's metric
// against THEIR OWN GT and butterfly-argmax (m, g) -> out_idx; out_fg set.
// Duplicate winners across GT columns write identical values — benign.
__global__ __launch_bounds__(64) void merge_assign_kernel(
    const float* __restrict__ pval,
    const int*   __restrict__ pidx,
    const float* __restrict__ pd_scores,
    const float* __restrict__ pd_bboxes,
    const float* __restrict__ anc_points,
    const float* __restrict__ gt_bboxes,
    int* __restrict__ out_fg,
    int* __restrict__ out_idx)
{
    const int g    = blockIdx.x;
    const int lane = threadIdx.x;   // == chunk for loading; == GT for argmax

    float4 mygt = ((const float4*)gt_bboxes)[lane];
    float  myga = (mygt.z - mygt.x) * (mygt.w - mygt.y);

    float tv[TOPK]; int ti[TOPK];
    const float* pv = pval + (g * CHUNKS + lane) * TOPK;
    const int*   pi = pidx + (g * CHUNKS + lane) * TOPK;
#pragma unroll
    for (int k = 0; k < TOPK; ++k) { tv[k] = pv[k]; ti[k] = pi[k]; }

#pragma unroll
    for (int k = 0; k < TOPK; ++k) {
        float bv = tv[0]; int bi = ti[0];
        wave_max_pair(bv, bi);
        bool win = (ti[0] == bi);
#pragma unroll
        for (int j = 0; j < TOPK - 1; ++j) {
            tv[j] = win ? tv[j + 1] : tv[j];
            ti[j] = win ? ti[j + 1] : ti[j];
        }
        if (win) { tv[TOPK - 1] = 0.0f; ti[TOPK - 1] = SENT_I; }

        if (bv > 0.0f) {            // wave-uniform: winner k is foreground
            const int a = bi;
            float2 ap = ((const float2*)anc_points)[a];   // uniform -> s_load
            float4 pb = ((const float4*)pd_bboxes)[a];
            float  sc = pd_scores[a];
            float parea = (pb.z - pb.x) * (pb.w - pb.y);
            bool in = (ap.x >= mygt.x) && (ap.x <= mygt.z) &&
                      (ap.y >= mygt.y) && (ap.y <= mygt.w);
            float m = iou_metric(pb.x, pb.y, pb.z, pb.w, parea,
                                 in ? sc : 0.0f,   // exact-0 when outside
                                 mygt.x, mygt.y, mygt.z, mygt.w, myga);
            // butterfly argmax over (m, gt=lane); lowest g on ties = first-max
            float av = m; int ag = lane;
#pragma unroll
            for (int s = 1; s < 64; s <<= 1) {
                float ov = __shfl_xor(av, s, 64);
                int   og = __shfl_xor(ag, s, 64);
                if ((ov > av) || ((ov == av) && (og < ag))) { av = ov; ag = og; }
            }
            if (lane == 0) { out_fg[a] = 1; out_idx[a] = ag; }
        }
    }
}

extern "C" void kernel_launch(void* const* d_in, const int* in_sizes, int n_in,
                              void* d_out, int out_size, void* d_ws, size_t ws_size,
                              hipStream_t stream) {
    const float* pd_scores  = (const float*)d_in[0];   // (A,1) f32
    const float* pd_bboxes  = (const float*)d_in[1];   // (A,4) f32
    const float* anc_points = (const float*)d_in[2];   // (A,2) f32
    // d_in[3] = gt_labels (G,) int32 — unused (NUM_CLASSES==1 -> all 0)
    const float* gt_bboxes  = (const float*)d_in[4];   // (G,4) f32

    const int npairs = NUM_G * CHUNKS * TOPK;          // 40960
    float* pval = (float*)d_ws;                        // 160 KB
    int*   pidx = (int*)(pval + npairs);               // 160 KB

    int* out_fg  = (int*)d_out;            // [fg(A) | idx(A)] as int32
    int* out_idx = out_fg + NUM_A;

    // zero BOTH output halves: non-winners get fg=0, idx=0
    hipMemsetAsync(d_out, 0, 2 * NUM_A * sizeof(int), stream);

    dim3 g1(CHUNKS, NGROUPS);
    topk_partial_kernel<<<g1, 256, 0, stream>>>(
        pd_scores, pd_bboxes, anc_points, gt_bboxes, pval, pidx);
    merge_assign_kernel<<<NUM_G, 64, 0, stream>>>(
        pval, pidx, pd_scores, pd_bboxes, anc_points, gt_bboxes,
        out_fg, out_idx);
}